// Round 6
// baseline (425.986 us; speedup 1.0000x reference)
//
#include <hip/hip_runtime.h>
#include <math.h>

// Problem constants
constexpr int Bq = 128;   // batch
constexpr int Nn = 512;   // nodes
constexpr int Dd = 300;   // feature dim
constexpr int Aa = 32;    // attention dim
constexpr int DT = 304;   // d padded to 19 tiles of 16 for MFMA N-dim

typedef __attribute__((ext_vector_type(8))) short short8;   // 8 bf16 (4 VGPRs)
typedef __attribute__((ext_vector_type(4))) float float4v;  // MFMA acc

static __device__ __forceinline__ ushort f2bf(float x) {
    unsigned u = __float_as_uint(x);
    return (ushort)((u + 0x7FFF + ((u >> 16) & 1)) >> 16);   // RNE
}

// ---------------- Kernel 1: Q/K projection (bf16 out) + bf16 X^T emission ----------------
constexpr int KB_ROWS = 128;
constexpr int DCHUNK = 100;      // 300 = 3 x 100
constexpr int XS_STRIDE = 102;

__global__ __launch_bounds__(256) void proj_qk(
    const float* __restrict__ X, const float* __restrict__ Wq,
    const float* __restrict__ Wk, ushort* __restrict__ Qo, ushort* __restrict__ Ko,
    ushort* __restrict__ XbfT)
{
    __shared__ float xs[KB_ROWS * XS_STRIDE];  // ~51 KB
    const int b  = blockIdx.y;
    const int n0 = blockIdx.x * KB_ROWS;
    const int t  = threadIdx.x;
    const int c  = t & 15;
    const int r  = t >> 4;
    const int a4 = c * 4;
    const int rbase = r * 8;
    const float* Wbase = (a4 < Aa) ? (Wq + a4) : (Wk + (a4 - Aa));
    const float* Xb = X + ((size_t)(b * Nn + n0)) * Dd;

    float4 acc[8];
#pragma unroll
    for (int j = 0; j < 8; ++j) acc[j] = make_float4(0.f, 0.f, 0.f, 0.f);

    for (int d0 = 0; d0 < Dd; d0 += DCHUNK) {
        for (int l = t; l < KB_ROWS * (DCHUNK / 2); l += 256) {
            int row = l / (DCHUNK / 2);
            int dd2 = l - row * (DCHUNK / 2);
            *(float2*)(xs + row * XS_STRIDE + dd2 * 2) =
                *(const float2*)(Xb + (size_t)row * Dd + d0 + dd2 * 2);
        }
        __syncthreads();
        for (int dd = 0; dd < DCHUNK; ++dd) {
            float4 w4 = *(const float4*)(Wbase + (size_t)(d0 + dd) * Aa);
#pragma unroll
            for (int j = 0; j < 8; ++j) {
                float xv = xs[(rbase + j) * XS_STRIDE + dd];
                acc[j].x += xv * w4.x; acc[j].y += xv * w4.y;
                acc[j].z += xv * w4.z; acc[j].w += xv * w4.w;
            }
        }
        // emit bf16 transposed chunk: XbfT[b][d0+dd][n0+row]
        for (int l = t; l < KB_ROWS * DCHUNK; l += 256) {
            int dd  = l >> 7;        // 12800 = 100 x 128
            int row = l & 127;
            XbfT[((size_t)b * DT + d0 + dd) * Nn + n0 + row] =
                f2bf(xs[row * XS_STRIDE + dd]);
        }
        __syncthreads();
    }

    ushort* Obase = (a4 < Aa) ? (Qo + a4) : (Ko + (a4 - Aa));
#pragma unroll
    for (int j = 0; j < 8; ++j) {
        int n = n0 + rbase + j;
        ushort4 o;
        o.x = f2bf(acc[j].x); o.y = f2bf(acc[j].y);
        o.z = f2bf(acc[j].z); o.w = f2bf(acc[j].w);
        *(ushort4*)(Obase + (size_t)(b * Nn + n) * Aa) = o;
    }
}

// ---------------- Kernel 1b: adjacency -> bitmask (32x traffic compression) ----------------
// Encoding: mask[b][n][8 words u64]; word j = h*4+jj holds bit l = adj[n][256*h + 4*l + jj].
// (This is exactly what per-lane float4 + __ballot produces; attn decodes it natively.)
__global__ __launch_bounds__(256) void adj_pack(
    const float* __restrict__ Adj, unsigned long long* __restrict__ Mask)
{
    const int blk = blockIdx.x;            // 2048 = 128 batches x 16 row-tiles
    const int b   = blk >> 4;
    const int n0  = (blk & 15) * 32;
    const int t    = threadIdx.x;
    const int lane = t & 63;
    const int wv   = t >> 6;

    const float* base = Adj + ((size_t)b * Nn + n0) * Nn;
#pragma unroll
    for (int rr = 0; rr < 8; ++rr) {
        const int row = wv * 8 + rr;
        const float* ap = base + (size_t)row * Nn + lane * 4;
        float4 v0 = *(const float4*)ap;          // cols 4*lane + {0..3}
        float4 v1 = *(const float4*)(ap + 256);  // cols 256 + 4*lane + {0..3}
        unsigned long long w0 = __ballot(v0.x != 0.f);
        unsigned long long w1 = __ballot(v0.y != 0.f);
        unsigned long long w2 = __ballot(v0.z != 0.f);
        unsigned long long w3 = __ballot(v0.w != 0.f);
        unsigned long long w4 = __ballot(v1.x != 0.f);
        unsigned long long w5 = __ballot(v1.y != 0.f);
        unsigned long long w6 = __ballot(v1.z != 0.f);
        unsigned long long w7 = __ballot(v1.w != 0.f);
        if (lane == 0) {
            unsigned long long* mp = Mask + ((size_t)b * Nn + n0 + row) * 8;
            mp[0] = w0; mp[1] = w1; mp[2] = w2; mp[3] = w3;
            mp[4] = w4; mp[5] = w5; mp[6] = w6; mp[7] = w7;
        }
    }
}

// ---------------- Kernel 2: cooperative attention (v4 base), bitmask adjacency ----------------
// v6 = v4 (best measured: 125us) with the 134MB fp32 adjacency stream replaced by the
// 4.2MB bitmask. Everything else identical: swapped QK^T phase 1, ds_write_b64 P-emits,
// lane-local denominators, paired-d-tile phase 3, launch_bounds(256,2).
constexpr int TN = 32;

__global__ __launch_bounds__(256, 2) void attn_kernel(
    const unsigned long long* __restrict__ Mask, const ushort* __restrict__ Qbf,
    const ushort* __restrict__ Kbf, const ushort* __restrict__ XbfT,
    float* __restrict__ Out)
{
    __shared__ __align__(16) ushort fragA[2 * 8192];   // 32 KB, A-frag-layout P (bf16)
    __shared__ __align__(16) float wsum[4][TN];

    // XCD swizzle: each XCD (blk%8) streams all 16 tiles of one batch consecutively
    const int blk  = blockIdx.x;
    const int b    = ((blk >> 7) << 3) | (blk & 7);
    const int n0   = ((blk >> 3) & 15) * TN;

    const int t    = threadIdx.x;
    const int lane = t & 63;
    const int wv   = t >> 6;
    const int dl   = lane & 15;
    const int quad = lane >> 4;

    // ---- Phase 1: S^T = mfma(K, Q); e = bit ? exp(S) : 1 -> fragA via b64 writes ----
    // D-layout: col = lane&15 = q (B free dim), row = quad*4+r = m-local.
    short8 qfr[2];   // B-operand: Q rows n0+rs*16+dl, a = quad*8..+7
#pragma unroll
    for (int rs = 0; rs < 2; ++rs)
        qfr[rs] = *(const short8*)(Qbf + ((size_t)(b * Nn + n0 + rs * 16 + dl)) * Aa + quad * 8);

    const ushort* Kb = Kbf + (size_t)b * Nn * Aa + (size_t)dl * Aa + quad * 8;
    // mask row base for q = n0 + dl (rs adds 16 rows)
    const unsigned long long* Mb = Mask + ((size_t)b * Nn + n0 + dl) * 8;

    float dsum[2] = {0.f, 0.f};
    // A-frag write base: elem = rs*8192 + ks*512 + (2h+(quad>>1))*128 + dl*8 + (quad&1)*4 + r
    ushort* wpb = fragA + (quad >> 1) * 128 + dl * 8 + (quad & 1) * 4;

#pragma unroll
    for (int i = 0; i < 4; ++i) {
        const int ks = wv + i * 4;      // this wave's 4 ks-tiles
        const int m0 = ks * 32;
        short8 kf0 = *(const short8*)(Kb + (size_t)m0 * Aa);          // K rows m0+dl   (h=0)
        short8 kf1 = *(const short8*)(Kb + (size_t)(m0 + 16) * Aa);   // K rows m0+16+dl (h=1)
        ushort* wp = wpb + ks * 512;
        const int hw    = (ks >> 3) * 4;              // word group (cols 0..255 vs 256..511)
        const int shift = ((ks & 7) << 3) + quad;     // bit for (h=0, col m0+quad*4+r); +4 for h=1
#pragma unroll
        for (int rs = 0; rs < 2; ++rs) {
            const unsigned long long* mrow = Mb + (size_t)rs * 16 * 8 + hw;
            ulonglong2 g0 = *(const ulonglong2*)(mrow);       // words r=0,1
            ulonglong2 g1 = *(const ulonglong2*)(mrow + 2);   // words r=2,3
            float4v z = {0.f, 0.f, 0.f, 0.f};
            float4v s0 = __builtin_amdgcn_mfma_f32_16x16x32_bf16(kf0, qfr[rs], z, 0, 0, 0);
            float4v s1 = __builtin_amdgcn_mfma_f32_16x16x32_bf16(kf1, qfr[rs], z, 0, 0, 0);
            // word index = r; bit = shift (h=0) / shift+4 (h=1)
            float e0 = ((g0.x >> shift) & 1ull)       ? __expf(s0[0]) : 1.0f;  // adj==0 -> e=1
            float e1 = ((g0.y >> shift) & 1ull)       ? __expf(s0[1]) : 1.0f;
            float e2 = ((g1.x >> shift) & 1ull)       ? __expf(s0[2]) : 1.0f;
            float e3 = ((g1.y >> shift) & 1ull)       ? __expf(s0[3]) : 1.0f;
            float e4 = ((g0.x >> (shift + 4)) & 1ull) ? __expf(s1[0]) : 1.0f;
            float e5 = ((g0.y >> (shift + 4)) & 1ull) ? __expf(s1[1]) : 1.0f;
            float e6 = ((g1.x >> (shift + 4)) & 1ull) ? __expf(s1[2]) : 1.0f;
            float e7 = ((g1.y >> (shift + 4)) & 1ull) ? __expf(s1[3]) : 1.0f;
            dsum[rs] += ((e0 + e1) + (e2 + e3)) + ((e4 + e5) + (e6 + e7));
            uint2 w0, w1;
            w0.x = (unsigned)f2bf(e0) | ((unsigned)f2bf(e1) << 16);
            w0.y = (unsigned)f2bf(e2) | ((unsigned)f2bf(e3) << 16);
            w1.x = (unsigned)f2bf(e4) | ((unsigned)f2bf(e5) << 16);
            w1.y = (unsigned)f2bf(e6) | ((unsigned)f2bf(e7) << 16);
            *(uint2*)(wp + rs * 8192)       = w0;   // h=0 chunk
            *(uint2*)(wp + rs * 8192 + 256) = w1;   // h=1 chunk (+2*128 elems)
        }
    }

    // ---- Phase 2: denominators. q-rows are lane-local (col=dl) -> 2 shuffles/wave ----
#pragma unroll
    for (int rs = 0; rs < 2; ++rs) {
        float v = dsum[rs];
        v += __shfl_xor(v, 16);
        v += __shfl_xor(v, 32);
        if (lane < 16) wsum[wv][rs * 16 + lane] = v;
    }
    __syncthreads();

    // Each lane finishes the cross-wave sum itself (float4 LDS reads, no 2nd barrier)
    float invr0[4], invr1[4];
    {
        float4 s0 = *(const float4*)&wsum[0][quad * 4];
        float4 s1 = *(const float4*)&wsum[0][16 + quad * 4];
#pragma unroll
        for (int w = 1; w < 4; ++w) {
            float4 t0 = *(const float4*)&wsum[w][quad * 4];
            float4 t1 = *(const float4*)&wsum[w][16 + quad * 4];
            s0.x += t0.x; s0.y += t0.y; s0.z += t0.z; s0.w += t0.w;
            s1.x += t1.x; s1.y += t1.y; s1.z += t1.z; s1.w += t1.w;
        }
        invr0[0] = 1.0f / s0.x; invr0[1] = 1.0f / s0.y;
        invr0[2] = 1.0f / s0.z; invr0[3] = 1.0f / s0.w;
        invr1[0] = 1.0f / s1.x; invr1[1] = 1.0f / s1.y;
        invr1[2] = 1.0f / s1.z; invr1[3] = 1.0f / s1.w;
    }

    // ---- Phase 3: Out[i][d] = inv[i] * sum_m e[i][m] * X[m][d] via MFMA (paired tiles) ----
    const ushort* Xb  = XbfT + ((size_t)b * DT) * Nn;
    const ushort* afp = fragA + (size_t)lane * 8;

    for (int p = 0; p < 3; ++p) {
        const int dta = wv + p * 8;
        if (dta >= DT / 16) break;
        const int dtb = dta + 4;
        if (dtb < DT / 16) {
            const ushort* bba = Xb + (size_t)(dta * 16 + dl) * Nn + quad * 8;
            const ushort* bbb = Xb + (size_t)(dtb * 16 + dl) * Nn + quad * 8;
            float4v a0a = {0.f, 0.f, 0.f, 0.f};
            float4v a1a = {0.f, 0.f, 0.f, 0.f};
            float4v a0b = {0.f, 0.f, 0.f, 0.f};
            float4v a1b = {0.f, 0.f, 0.f, 0.f};
#pragma unroll
            for (int ks = 0; ks < 16; ++ks) {
                short8 bfa = *(const short8*)(bba + ks * 32);
                short8 bfb = *(const short8*)(bbb + ks * 32);
                short8 p0  = *(const short8*)(afp + ks * 512);
                short8 p1  = *(const short8*)(afp + 8192 + ks * 512);
                a0a = __builtin_amdgcn_mfma_f32_16x16x32_bf16(p0, bfa, a0a, 0, 0, 0);
                a1a = __builtin_amdgcn_mfma_f32_16x16x32_bf16(p1, bfa, a1a, 0, 0, 0);
                a0b = __builtin_amdgcn_mfma_f32_16x16x32_bf16(p0, bfb, a0b, 0, 0, 0);
                a1b = __builtin_amdgcn_mfma_f32_16x16x32_bf16(p1, bfb, a1b, 0, 0, 0);
            }
            const int da = dta * 16 + dl;   // <= 191, no guard needed
            const int db = dtb * 16 + dl;   // <= 255, no guard needed
#pragma unroll
            for (int r = 0; r < 4; ++r) {
                float* o0 = Out + ((size_t)(b * Nn + n0 + quad * 4 + r)) * Dd;
                float* o1 = Out + ((size_t)(b * Nn + n0 + 16 + quad * 4 + r)) * Dd;
                o0[da] = a0a[r] * invr0[r];
                o1[da] = a1a[r] * invr1[r];
                o0[db] = a0b[r] * invr0[r];
                o1[db] = a1b[r] * invr1[r];
            }
        } else {
            const ushort* bb = Xb + (size_t)(dta * 16 + dl) * Nn + quad * 8;
            float4v acc0 = {0.f, 0.f, 0.f, 0.f};
            float4v acc1 = {0.f, 0.f, 0.f, 0.f};
#pragma unroll
            for (int ks = 0; ks < 16; ++ks) {
                short8 bf = *(const short8*)(bb + ks * 32);
                short8 p0 = *(const short8*)(afp + ks * 512);
                short8 p1 = *(const short8*)(afp + 8192 + ks * 512);
                acc0 = __builtin_amdgcn_mfma_f32_16x16x32_bf16(p0, bf, acc0, 0, 0, 0);
                acc1 = __builtin_amdgcn_mfma_f32_16x16x32_bf16(p1, bf, acc1, 0, 0, 0);
            }
            const int d = dta * 16 + dl;
            if (d < Dd) {
#pragma unroll
                for (int r = 0; r < 4; ++r) {
                    Out[((size_t)(b * Nn + n0 + quad * 4 + r)) * Dd + d]      = acc0[r] * invr0[r];
                    Out[((size_t)(b * Nn + n0 + 16 + quad * 4 + r)) * Dd + d] = acc1[r] * invr1[r];
                }
            }
        }
    }
}

// ---------------- launch ----------------
extern "C" void kernel_launch(void* const* d_in, const int* in_sizes, int n_in,
                              void* d_out, int out_size, void* d_ws, size_t ws_size,
                              hipStream_t stream) {
    const float* X   = (const float*)d_in[0];   // [128,512,300]
    const float* Adj = (const float*)d_in[1];   // [128,512,512]
    const float* Wq  = (const float*)d_in[2];   // [300,32]
    const float* Wk  = (const float*)d_in[3];   // [300,32]
    float* Out = (float*)d_out;                 // [128,512,300]

    ushort* Qbf  = (ushort*)d_ws;                                      // 4 MB
    ushort* Kbf  = (ushort*)((char*)d_ws + (size_t)4 * 1024 * 1024);   // 4 MB
    ushort* XbfT = (ushort*)((char*)d_ws + (size_t)8 * 1024 * 1024);   // ~38 MB
    unsigned long long* Mask =
        (unsigned long long*)((char*)d_ws + (size_t)48 * 1024 * 1024); // 4 MB bitmask

    proj_qk<<<dim3(Nn / KB_ROWS, Bq), 256, 0, stream>>>(X, Wq, Wk, Qbf, Kbf, XbfT);
    adj_pack<<<dim3(Bq * Nn / 32), 256, 0, stream>>>(Adj, Mask);
    attn_kernel<<<dim3(Bq * Nn / TN), 256, 0, stream>>>(Mask, Qbf, Kbf, XbfT, Out);
}

// Round 7
// 395.470 us; speedup vs baseline: 1.0772x; 1.0772x over previous
//
#include <hip/hip_runtime.h>
#include <math.h>

// Problem constants
constexpr int Bq = 128;   // batch
constexpr int Nn = 512;   // nodes
constexpr int Dd = 300;   // feature dim
constexpr int Aa = 32;    // attention dim
constexpr int DT = 304;   // d padded to 19 tiles of 16 for MFMA N-dim

typedef __attribute__((ext_vector_type(8))) short short8;   // 8 bf16 (4 VGPRs)
typedef __attribute__((ext_vector_type(4))) float float4v;  // MFMA acc

static __device__ __forceinline__ ushort f2bf(float x) {
    unsigned u = __float_as_uint(x);
    return (ushort)((u + 0x7FFF + ((u >> 16) & 1)) >> 16);   // RNE
}
static __device__ __forceinline__ unsigned pack2(float lo, float hi) {
    return (unsigned)f2bf(lo) | ((unsigned)f2bf(hi) << 16);
}

// ---------------- Kernel 1: MFMA Q/K projection + bf16 X^T emission ----------------
// v7: replaces the scalar-FMA proj (9600 v_fmac + 9600 ds_read_b32 per thread,
// MfmaUtil=0, 111us) with an MFMA GEMM: [128x320]x[320x64] per block.
// W staged transposed in LDS (zero-padded k>=300); X staged per 64-k chunk as bf16
// (converted once), reused for XbfT emission AND A-fragments.
constexpr int PB_ROWS = 128;
constexpr int WK   = 320;   // padded K for W in LDS (5 chunks x 64)
constexpr int WSTR = 328;   // wl row stride (bank-friendly: 656B -> 2-way)
constexpr int XSTR = 72;    // xs row stride in bf16 (144B -> 2-way)

__global__ __launch_bounds__(256) void proj_qk(
    const float* __restrict__ X, const float* __restrict__ Wq,
    const float* __restrict__ Wk, ushort* __restrict__ Qo, ushort* __restrict__ Ko,
    ushort* __restrict__ XbfT)
{
    __shared__ __align__(16) ushort wl[64 * WSTR];       // [col][k] bf16, 41.0 KB
    __shared__ __align__(16) ushort xs[PB_ROWS * XSTR];  // [row][k-local] bf16, 18.4 KB

    const int b  = blockIdx.y;
    const int n0 = blockIdx.x * PB_ROWS;
    const int t    = threadIdx.x;
    const int lane = t & 63;
    const int wv   = t >> 6;
    const int dl   = lane & 15;
    const int quad = lane >> 4;

    // ---- W -> LDS, transposed + padded: wl[col][k]; col 0-31=Wq, 32-63=Wk ----
    for (int l = t; l < 64 * WK; l += 256) {
        const int k = l >> 6, col = l & 63;
        float v = 0.f;
        if (k < Dd) v = (col < 32) ? Wq[k * 32 + col] : Wk[k * 32 + (col - 32)];
        wl[col * WSTR + k] = f2bf(v);
    }

    const float* Xb = X + ((size_t)(b * Nn + n0)) * Dd;
    const int colb = wv * 16 + dl;          // this wave's W column (col-tile = wv)

    float4v acc[8];
#pragma unroll
    for (int rt = 0; rt < 8; ++rt) acc[rt] = (float4v){0.f, 0.f, 0.f, 0.f};

    for (int c = 0; c < 5; ++c) {
        __syncthreads();   // covers wl fill (c==0) and previous chunk's readers
        // ---- stage X chunk (f32 -> bf16), zero beyond d>=300 ----
        for (int s = t; s < PB_ROWS * 16; s += 256) {
            const int row = s >> 4, f4 = s & 15;
            const int d = c * 64 + f4 * 4;
            float4 v = make_float4(0.f, 0.f, 0.f, 0.f);
            if (d < Dd) v = *(const float4*)(Xb + (size_t)row * Dd + d);  // d<=296 -> d+3<=299
            uint2 pk;
            pk.x = pack2(v.x, v.y);
            pk.y = pack2(v.z, v.w);
            *(uint2*)(xs + row * XSTR + f4 * 4) = pk;
        }
        __syncthreads();

        // ---- emit XbfT chunk: XbfT[b][d][n0+row], short8 per 8 rows ----
        for (int s = t; s < 64 * 16; s += 256) {
            const int dloc = s >> 4, rg = s & 15;
            const int d = c * 64 + dloc;
            if (d < Dd) {
                short8 o;
#pragma unroll
                for (int i = 0; i < 8; ++i) o[i] = (short)xs[(rg * 8 + i) * XSTR + dloc];
                *(short8*)(XbfT + ((size_t)b * DT + d) * Nn + n0 + rg * 8) = o;
            }
        }

        // ---- MFMA: acc[rt] += X[rt*16+dl][k..] * W[k..][colb] over this chunk ----
        short8 bf0 = *(const short8*)(wl + colb * WSTR + c * 64 + quad * 8);        // kk=0
        short8 bf1 = *(const short8*)(wl + colb * WSTR + c * 64 + 32 + quad * 8);   // kk=1
#pragma unroll
        for (int rt = 0; rt < 8; ++rt) {
            short8 a0 = *(const short8*)(xs + (rt * 16 + dl) * XSTR + quad * 8);
            short8 a1 = *(const short8*)(xs + (rt * 16 + dl) * XSTR + 32 + quad * 8);
            acc[rt] = __builtin_amdgcn_mfma_f32_16x16x32_bf16(a0, bf0, acc[rt], 0, 0, 0);
            acc[rt] = __builtin_amdgcn_mfma_f32_16x16x32_bf16(a1, bf1, acc[rt], 0, 0, 0);
        }
    }

    // ---- store Q/K bf16: D[row=rt*16+quad*4+r][col=colb] ----
    ushort* Obase = (wv < 2) ? Qo : Ko;
    const int cbase = (wv & 1) * 16 + dl;
#pragma unroll
    for (int rt = 0; rt < 8; ++rt) {
#pragma unroll
        for (int r = 0; r < 4; ++r) {
            const int row = n0 + rt * 16 + quad * 4 + r;
            Obase[((size_t)(b * Nn + row)) * Aa + cbase] = f2bf(acc[rt][r]);
        }
    }
}

// ---------------- Kernel 2: cooperative attention (v4, best measured: 125us) ----------------
// Direct Adj reads (r6 lesson: Adj has zero reuse across blocks -> pre-packing just
// moves the stream, attn barely changed; adj_pack deleted).
constexpr int TN = 32;

__global__ __launch_bounds__(256, 2) void attn_kernel(
    const float* __restrict__ Adj, const ushort* __restrict__ Qbf,
    const ushort* __restrict__ Kbf, const ushort* __restrict__ XbfT,
    float* __restrict__ Out)
{
    __shared__ __align__(16) ushort fragA[2 * 8192];   // 32 KB, A-frag-layout P (bf16)
    __shared__ __align__(16) float wsum[4][TN];

    // XCD swizzle: each XCD (blk%8) streams all 16 tiles of one batch consecutively
    const int blk  = blockIdx.x;
    const int b    = ((blk >> 7) << 3) | (blk & 7);
    const int n0   = ((blk >> 3) & 15) * TN;

    const int t    = threadIdx.x;
    const int lane = t & 63;
    const int wv   = t >> 6;
    const int dl   = lane & 15;
    const int quad = lane >> 4;

    // ---- Phase 1: S^T = mfma(K, Q); e = adj ? exp(S) : 1 -> fragA via b64 writes ----
    // D-layout: col = lane&15 = q (B free dim), row = quad*4+r = m-local.
    short8 qfr[2];   // B-operand: Q rows n0+rs*16+dl, a = quad*8..+7
#pragma unroll
    for (int rs = 0; rs < 2; ++rs)
        qfr[rs] = *(const short8*)(Qbf + ((size_t)(b * Nn + n0 + rs * 16 + dl)) * Aa + quad * 8);

    const ushort* Kb    = Kbf + (size_t)b * Nn * Aa + (size_t)dl * Aa + quad * 8;
    const float*  arow0 = Adj + ((size_t)b * Nn + n0 + dl) * Nn + quad * 4;

    float dsum[2] = {0.f, 0.f};
    // A-frag write base: elem = rs*8192 + ks*512 + (2h+(quad>>1))*128 + dl*8 + (quad&1)*4 + r
    ushort* wpb = fragA + (quad >> 1) * 128 + dl * 8 + (quad & 1) * 4;

#pragma unroll
    for (int i = 0; i < 4; ++i) {
        const int ks = wv + i * 4;      // this wave's 4 ks-tiles (static trip count)
        const int m0 = ks * 32;
        short8 kf0 = *(const short8*)(Kb + (size_t)m0 * Aa);          // K rows m0+dl   (h=0)
        short8 kf1 = *(const short8*)(Kb + (size_t)(m0 + 16) * Aa);   // K rows m0+16+dl (h=1)
        ushort* wp = wpb + ks * 512;
#pragma unroll
        for (int rs = 0; rs < 2; ++rs) {
            const float* ar = arow0 + (size_t)rs * 16 * Nn + m0;   // adj[q=rs*16+dl][m0+quad*4..]
            float4 a0 = *(const float4*)(ar);          // h=0: m = m0+quad*4+r
            float4 a1 = *(const float4*)(ar + 16);     // h=1: m = m0+16+quad*4+r
            float4v z = {0.f, 0.f, 0.f, 0.f};
            float4v s0 = __builtin_amdgcn_mfma_f32_16x16x32_bf16(kf0, qfr[rs], z, 0, 0, 0);
            float4v s1 = __builtin_amdgcn_mfma_f32_16x16x32_bf16(kf1, qfr[rs], z, 0, 0, 0);
            float e0 = (a0.x != 0.f) ? __expf(s0[0]) : 1.0f;   // adj==0 -> e=1 exactly
            float e1 = (a0.y != 0.f) ? __expf(s0[1]) : 1.0f;
            float e2 = (a0.z != 0.f) ? __expf(s0[2]) : 1.0f;
            float e3 = (a0.w != 0.f) ? __expf(s0[3]) : 1.0f;
            float e4 = (a1.x != 0.f) ? __expf(s1[0]) : 1.0f;
            float e5 = (a1.y != 0.f) ? __expf(s1[1]) : 1.0f;
            float e6 = (a1.z != 0.f) ? __expf(s1[2]) : 1.0f;
            float e7 = (a1.w != 0.f) ? __expf(s1[3]) : 1.0f;
            dsum[rs] += ((e0 + e1) + (e2 + e3)) + ((e4 + e5) + (e6 + e7));
            uint2 w0, w1;
            w0.x = (unsigned)f2bf(e0) | ((unsigned)f2bf(e1) << 16);
            w0.y = (unsigned)f2bf(e2) | ((unsigned)f2bf(e3) << 16);
            w1.x = (unsigned)f2bf(e4) | ((unsigned)f2bf(e5) << 16);
            w1.y = (unsigned)f2bf(e6) | ((unsigned)f2bf(e7) << 16);
            *(uint2*)(wp + rs * 8192)       = w0;   // h=0 chunk
            *(uint2*)(wp + rs * 8192 + 256) = w1;   // h=1 chunk (+2*128 elems)
        }
    }

    // ---- Phase 2: denominators. q-rows are lane-local (col=dl) -> 2 shuffles/wave ----
#pragma unroll
    for (int rs = 0; rs < 2; ++rs) {
        float v = dsum[rs];
        v += __shfl_xor(v, 16);
        v += __shfl_xor(v, 32);
        if (lane < 16) wsum[wv][rs * 16 + lane] = v;
    }
    __syncthreads();

    // Each lane finishes the cross-wave sum itself (float4 LDS reads, no 2nd barrier)
    float invr0[4], invr1[4];
    {
        float4 s0 = *(const float4*)&wsum[0][quad * 4];
        float4 s1 = *(const float4*)&wsum[0][16 + quad * 4];
#pragma unroll
        for (int w = 1; w < 4; ++w) {
            float4 t0 = *(const float4*)&wsum[w][quad * 4];
            float4 t1 = *(const float4*)&wsum[w][16 + quad * 4];
            s0.x += t0.x; s0.y += t0.y; s0.z += t0.z; s0.w += t0.w;
            s1.x += t1.x; s1.y += t1.y; s1.z += t1.z; s1.w += t1.w;
        }
        invr0[0] = 1.0f / s0.x; invr0[1] = 1.0f / s0.y;
        invr0[2] = 1.0f / s0.z; invr0[3] = 1.0f / s0.w;
        invr1[0] = 1.0f / s1.x; invr1[1] = 1.0f / s1.y;
        invr1[2] = 1.0f / s1.z; invr1[3] = 1.0f / s1.w;
    }

    // ---- Phase 3: Out[i][d] = inv[i] * sum_m e[i][m] * X[m][d] via MFMA (paired tiles) ----
    const ushort* Xb  = XbfT + ((size_t)b * DT) * Nn;
    const ushort* afp = fragA + (size_t)lane * 8;

    for (int p = 0; p < 3; ++p) {
        const int dta = wv + p * 8;
        if (dta >= DT / 16) break;
        const int dtb = dta + 4;
        if (dtb < DT / 16) {
            const ushort* bba = Xb + (size_t)(dta * 16 + dl) * Nn + quad * 8;
            const ushort* bbb = Xb + (size_t)(dtb * 16 + dl) * Nn + quad * 8;
            float4v a0a = {0.f, 0.f, 0.f, 0.f};
            float4v a1a = {0.f, 0.f, 0.f, 0.f};
            float4v a0b = {0.f, 0.f, 0.f, 0.f};
            float4v a1b = {0.f, 0.f, 0.f, 0.f};
#pragma unroll
            for (int ks = 0; ks < 16; ++ks) {
                short8 bfa = *(const short8*)(bba + ks * 32);
                short8 bfb = *(const short8*)(bbb + ks * 32);
                short8 p0  = *(const short8*)(afp + ks * 512);
                short8 p1  = *(const short8*)(afp + 8192 + ks * 512);
                a0a = __builtin_amdgcn_mfma_f32_16x16x32_bf16(p0, bfa, a0a, 0, 0, 0);
                a1a = __builtin_amdgcn_mfma_f32_16x16x32_bf16(p1, bfa, a1a, 0, 0, 0);
                a0b = __builtin_amdgcn_mfma_f32_16x16x32_bf16(p0, bfb, a0b, 0, 0, 0);
                a1b = __builtin_amdgcn_mfma_f32_16x16x32_bf16(p1, bfb, a1b, 0, 0, 0);
            }
            const int da = dta * 16 + dl;   // <= 191, no guard needed
            const int db = dtb * 16 + dl;   // <= 255, no guard needed
#pragma unroll
            for (int r = 0; r < 4; ++r) {
                float* o0 = Out + ((size_t)(b * Nn + n0 + quad * 4 + r)) * Dd;
                float* o1 = Out + ((size_t)(b * Nn + n0 + 16 + quad * 4 + r)) * Dd;
                o0[da] = a0a[r] * invr0[r];
                o1[da] = a1a[r] * invr1[r];
                o0[db] = a0b[r] * invr0[r];
                o1[db] = a1b[r] * invr1[r];
            }
        } else {
            const ushort* bb = Xb + (size_t)(dta * 16 + dl) * Nn + quad * 8;
            float4v acc0 = {0.f, 0.f, 0.f, 0.f};
            float4v acc1 = {0.f, 0.f, 0.f, 0.f};
#pragma unroll
            for (int ks = 0; ks < 16; ++ks) {
                short8 bf = *(const short8*)(bb + ks * 32);
                short8 p0 = *(const short8*)(afp + ks * 512);
                short8 p1 = *(const short8*)(afp + 8192 + ks * 512);
                acc0 = __builtin_amdgcn_mfma_f32_16x16x32_bf16(p0, bf, acc0, 0, 0, 0);
                acc1 = __builtin_amdgcn_mfma_f32_16x16x32_bf16(p1, bf, acc1, 0, 0, 0);
            }
            const int d = dta * 16 + dl;
            if (d < Dd) {
#pragma unroll
                for (int r = 0; r < 4; ++r) {
                    Out[((size_t)(b * Nn + n0 + quad * 4 + r)) * Dd + d]      = acc0[r] * invr0[r];
                    Out[((size_t)(b * Nn + n0 + 16 + quad * 4 + r)) * Dd + d] = acc1[r] * invr1[r];
                }
            }
        }
    }
}

// ---------------- launch ----------------
extern "C" void kernel_launch(void* const* d_in, const int* in_sizes, int n_in,
                              void* d_out, int out_size, void* d_ws, size_t ws_size,
                              hipStream_t stream) {
    const float* X   = (const float*)d_in[0];   // [128,512,300]
    const float* Adj = (const float*)d_in[1];   // [128,512,512]
    const float* Wq  = (const float*)d_in[2];   // [300,32]
    const float* Wk  = (const float*)d_in[3];   // [300,32]
    float* Out = (float*)d_out;                 // [128,512,300]

    ushort* Qbf  = (ushort*)d_ws;                                      // 4 MB
    ushort* Kbf  = (ushort*)((char*)d_ws + (size_t)4 * 1024 * 1024);   // 4 MB
    ushort* XbfT = (ushort*)((char*)d_ws + (size_t)8 * 1024 * 1024);   // ~39.9 MB

    proj_qk<<<dim3(Nn / PB_ROWS, Bq), 256, 0, stream>>>(X, Wq, Wk, Qbf, Kbf, XbfT);
    attn_kernel<<<dim3(Bq * Nn / TN), 256, 0, stream>>>(Adj, Qbf, Kbf, XbfT, Out);
}